// Round 19
// baseline (88.559 us; speedup 1.0000x reference)
//
#include <hip/hip_runtime.h>
#include <hip/hip_bf16.h>

typedef __attribute__((ext_vector_type(8))) short bf16x8;
typedef __attribute__((ext_vector_type(4))) float f32x4;

#define N_TOKENS 16384
#define DIM 4096
#define TOKB 32            // tokens per block
#define BK 128             // K floats per staged tile
#define NIT (DIM / BK)     // 32 iterations
#define NBUF 4
#define BUF_F (TOKB * BK)  // 4096 floats (16 KB) per buffer
#define N_EXP 64

// d_out layout (all float32):
//   [0, 32768)              topk_experts as float  [token][2]
//   [32768, 65536)          combine_weight         [token][2]
//   [65536, 65536+1048576)  scores                 [token][64]
//   [1114112]               load_balance_loss
//   [1114113]               z_loss
#define OFF_W   (N_TOKENS * 2)
#define OFF_S   (N_TOKENS * 4)
#define OFF_LBL (N_TOKENS * 4 + N_TOKENS * N_EXP)
#define OFF_Z   (OFF_LBL + 1)

// ws layout (floats): [0..63] me, [64..127] ce, [128] z,
// [512..) w_hi packed ushort[64*4096] (512 KB), then w_lo packed ushort[64*4096]
#define WS_WHI_F 512
#define WS_WLO_F (512 + (N_EXP * DIM) / 2)

typedef const __attribute__((address_space(1))) void GV;
typedef __attribute__((address_space(3))) void LV;

// ---- cheap truncation split: f = hi + r exactly; lo = trunc(r). ~3 VALU/elem.
__device__ __forceinline__ unsigned int pkhi(float a, float b) {
  return __builtin_amdgcn_perm(__float_as_uint(b), __float_as_uint(a), 0x07060302u);
}
__device__ __forceinline__ float resid(float f) {
  return f - __uint_as_float(__float_as_uint(f) & 0xFFFF0000u);
}
__device__ __forceinline__ void tsplit8(const f32x4 p0, const f32x4 p1,
                                        bf16x8& hi, bf16x8& lo) {
  uint4 H = make_uint4(pkhi(p0[0], p0[1]), pkhi(p0[2], p0[3]),
                       pkhi(p1[0], p1[1]), pkhi(p1[2], p1[3]));
  float r0 = resid(p0[0]), r1 = resid(p0[1]), r2 = resid(p0[2]), r3 = resid(p0[3]);
  float r4 = resid(p1[0]), r5 = resid(p1[1]), r6 = resid(p1[2]), r7 = resid(p1[3]);
  uint4 L = make_uint4(pkhi(r0, r1), pkhi(r2, r3), pkhi(r4, r5), pkhi(r6, r7));
  hi = __builtin_bit_cast(bf16x8, H);
  lo = __builtin_bit_cast(bf16x8, L);
}

// pre-pass: w fp32 -> bf16 hi/lo planes, PRE-PACKED into MFMA fragment order.
// plane layout: [kq(4)][q(2)][it(32)][n(2)][lane(64)*8 ushorts]
//   source (e,k): q=e>>5, n=(e>>4)&1, r15=e&15; it=k>>7, kq=(k>>5)&3,
//   half=(k>>3)&3, j=k&7; lane = half*16 + r15.
__global__ __launch_bounds__(256) void split_w_kernel(
    const float* __restrict__ w,
    unsigned short* __restrict__ whi, unsigned short* __restrict__ wlo)
{
  const int i = blockIdx.x * 256 + threadIdx.x;  // 0 .. 64*4096-1
  const int e = i >> 12, k = i & 4095;
  float f = w[i];
  unsigned short h = __builtin_bit_cast(unsigned short, __float2bfloat16(f));
  float hf = __uint_as_float(((unsigned)h) << 16);
  unsigned short l = __builtin_bit_cast(unsigned short, __float2bfloat16(f - hf));
  const int q = e >> 5, n = (e >> 4) & 1, r15 = e & 15;
  const int it = k >> 7, kq = (k >> 5) & 3, half = (k >> 3) & 3, j = k & 7;
  const int lane = half * 16 + r15;
  const int idx = (((kq * 2 + q) * 32 + it) * 1024) + n * 512 + lane * 8 + j;
  whi[idx] = h;
  wlo[idx] = l;
}

__global__ __launch_bounds__(512, 4) void router_kernel(
    const float* __restrict__ x,
    const unsigned short* __restrict__ whi, const unsigned short* __restrict__ wlo,
    float* __restrict__ out, float* __restrict__ ws)
{
  // 4 linear fp32 x-tile buffers [32][128] (64 KB); reused as logits in epilogue.
  // Content is source-swizzled at 16B granularity: LDS[row][u] = x[row][u ^ (row&7)]
  __shared__ __align__(16) float smem[NBUF * BUF_F];

  const int tid  = threadIdx.x;
  const int lane = tid & 63;
  const int wv   = __builtin_amdgcn_readfirstlane(tid >> 6);  // 0..7, wave-uniform
  const int q    = wv & 1;     // expert half (32 experts)
  const int kq   = wv >> 1;    // k-slice: 0..3 (32 floats each within BK)
  const int half = lane >> 4;  // 0..3
  const int r15  = lane & 15;
  const int tok0 = blockIdx.x * TOKB;

  // staging: wave wv covers rows wv*4..+3 of the [32][128] tile
  const int row0 = wv * 4 + (lane >> 5);
  const int row1 = row0 + 2;
  const int sU   = lane & 31;
  const float* g0 = x + (size_t)(tok0 + row0) * DIM + ((sU ^ (row0 & 7)) << 2);
  const float* g1 = x + (size_t)(tok0 + row1) * DIM + ((sU ^ (row1 & 7)) << 2);
  float* const ldst = smem + wv * 512;  // wave-uniform

#define STAGE(buf, it_) do {                                                  \
    const float* s0_ = g0 + (size_t)(it_) * BK;                               \
    const float* s1_ = g1 + (size_t)(it_) * BK;                               \
    float* d_ = ldst + (buf) * BUF_F;                                         \
    __builtin_amdgcn_global_load_lds((GV*)s0_, (LV*)d_,       16, 0, 0);      \
    __builtin_amdgcn_global_load_lds((GV*)s1_, (LV*)(d_+256), 16, 0, 0);      \
  } while (0)

  // packed w: this wave's contiguous 64 KB region per plane, walked linearly
  const unsigned short* wph = whi + ((kq * 2 + q) << 15);  // *32768 ushorts
  const unsigned short* wpl = wlo + ((kq * 2 + q) << 15);
  const int lo16 = lane * 8;  // lane's 16B slot within each 1KB cell

  f32x4 acc[2][2];
#pragma unroll
  for (int tt = 0; tt < 2; ++tt)
#pragma unroll
    for (int n = 0; n < 2; ++n) acc[tt][n] = (f32x4){0.f, 0.f, 0.f, 0.f};

  // ---- prologue: FIFO = stage0(2), stage1(2), stage2(2) ----
  STAGE(0, 0);
  STAGE(1, 1);
  STAGE(2, 2);

  for (int it = 0; it < NIT; ++it) {
    const int cur = it & 3;
    // 4 coalesced w-loads for this iter (1 KB contiguous per wave each)
    const unsigned short* ph = wph + it * 1024;
    const unsigned short* pl = wpl + it * 1024;
    bf16x8 bh0 = *(const bf16x8*)(ph + lo16);
    bf16x8 bh1 = *(const bf16x8*)(ph + 512 + lo16);
    bf16x8 bl0 = *(const bf16x8*)(pl + lo16);
    bf16x8 bl1 = *(const bf16x8*)(pl + 512 + lo16);

    // wait: newest 8 ops = this iter's w(4) + stage(it+2)(2) + stage(it+1)(2);
    // vmcnt(8) retires exactly stage(it) (3-iteration cover), keeps the rest flying.
    asm volatile("s_waitcnt vmcnt(8)" ::: "memory");
    __builtin_amdgcn_s_barrier();

    // stage it+3, issued AFTER the barrier: its buffer ((it+3)&3 == (it-1)&3) was
    // being read by other waves until this barrier -- no WAR race now.
    STAGE((it + 3) & 3, (it + 3 < NIT) ? it + 3 : NIT - 1);

    // ---- compute from buf cur: swizzled fp32 reads -> trunc-split -> 12 MFMA ----
    const float* bufp = smem + cur * BUF_F;
#pragma unroll
    for (int tt = 0; tt < 2; ++tt) {
      const int rowA = tt * 16 + r15;
      const int g    = r15 & 7;
      const float* rp = bufp + rowA * BK;
      const int u0 = kq * 8 + ((half * 2) ^ g);
      const int u1 = kq * 8 + ((half * 2 + 1) ^ g);
      f32x4 p0 = *(const f32x4*)(rp + (u0 << 2));
      f32x4 p1 = *(const f32x4*)(rp + (u1 << 2));
      bf16x8 ah, al;
      tsplit8(p0, p1, ah, al);
      acc[tt][0] = __builtin_amdgcn_mfma_f32_16x16x32_bf16(ah, bh0, acc[tt][0], 0, 0, 0);
      acc[tt][0] = __builtin_amdgcn_mfma_f32_16x16x32_bf16(al, bh0, acc[tt][0], 0, 0, 0);
      acc[tt][0] = __builtin_amdgcn_mfma_f32_16x16x32_bf16(ah, bl0, acc[tt][0], 0, 0, 0);
      acc[tt][1] = __builtin_amdgcn_mfma_f32_16x16x32_bf16(ah, bh1, acc[tt][1], 0, 0, 0);
      acc[tt][1] = __builtin_amdgcn_mfma_f32_16x16x32_bf16(al, bh1, acc[tt][1], 0, 0, 0);
      acc[tt][1] = __builtin_amdgcn_mfma_f32_16x16x32_bf16(ah, bl1, acc[tt][1], 0, 0, 0);
    }
  }

  // drain all outstanding gll writes (incl. clamped tail stages) before smem reuse
  asm volatile("s_waitcnt vmcnt(0)" ::: "memory");
  __syncthreads();

  // ---- epilogue: reuse smem as 4 kq-partial logit buffers [32][65] ----
  float* lb = smem;
  {
    float* dst = lb + kq * (TOKB * 65);
#pragma unroll
    for (int tt = 0; tt < 2; ++tt) {
#pragma unroll
      for (int n = 0; n < 2; ++n) {
#pragma unroll
        for (int r = 0; r < 4; ++r) {
          dst[(tt * 16 + half * 4 + r) * 65 + q * 32 + n * 16 + r15] = acc[tt][n][r];
        }
      }
    }
  }
  __syncthreads();

  // combine the four kq partials
  for (int i = tid; i < TOKB * 64; i += 512) {
    const int t = i >> 6, e = i & 63;
    lb[t * 65 + e] += lb[2080 + t * 65 + e] + lb[4160 + t * 65 + e] + lb[6240 + t * 65 + e];
  }
  __syncthreads();

  if (wv == 0 && lane < TOKB) {
    // lane owns one token: full softmax + top-2 + z-loss
    const int token = tok0 + lane;
    float v[64];
#pragma unroll
    for (int e = 0; e < 64; ++e) v[e] = lb[lane * 65 + e];
    float m = v[0];
#pragma unroll
    for (int e = 1; e < 64; ++e) m = fmaxf(m, v[e]);
    float sum = 0.f;
#pragma unroll
    for (int e = 0; e < 64; ++e) { v[e] = expf(v[e] - m); sum += v[e]; }
    const float inv = 1.0f / sum;
    float m1 = -1.f, m2 = -1.f;
    int   i1 = 0,    i2 = 0;
#pragma unroll
    for (int e = 0; e < 64; ++e) {
      float sc = v[e] * inv;
      lb[lane * 65 + e] = sc;
      if (sc > m1)      { m2 = m1; i2 = i1; m1 = sc; i1 = e; }
      else if (sc > m2) { m2 = sc; i2 = e; }
    }
    out[2 * token]         = (float)i1;
    out[2 * token + 1]     = (float)i2;
    out[OFF_W + 2 * token]     = m1;
    out[OFF_W + 2 * token + 1] = m2;

    float lse = m + logf(sum);
    float z = lse * lse;
#pragma unroll
    for (int off = 16; off > 0; off >>= 1) z += __shfl_down(z, off);
    if (lane == 0) atomicAdd(ws + 128, z);
  }
  __syncthreads();

  // coalesced scores store for this block's 32 tokens
  float* outS = out + OFF_S + (size_t)blockIdx.x * TOKB * 64;
  for (int i = tid; i < TOKB * 64; i += 512) {
    outS[i] = lb[(i >> 6) * 65 + (i & 63)];
  }

  // per-expert partial me / ce for this block's tokens (expert = lane)
  if (wv == 0) {
    float sm = 0.f, cn = 0.f;
#pragma unroll
    for (int t = 0; t < TOKB; ++t) {
      float sc = lb[t * 65 + lane];
      sm += sc;
      cn += (sc > 0.f) ? 1.f : 0.f;
    }
    atomicAdd(ws + lane, sm);
    atomicAdd(ws + 64 + lane, cn);
  }
#undef STAGE
}

__global__ void finalize_kernel(const float* __restrict__ ws, float* __restrict__ out) {
  const int l = threadIdx.x;  // 64 threads
  const float invT = 1.0f / (float)N_TOKENS;
  float me = ws[l] * invT;
  float ce = ws[64 + l] * invT;
  float p = me * ce;
#pragma unroll
  for (int off = 32; off > 0; off >>= 1) p += __shfl_down(p, off);
  if (l == 0) {
    out[OFF_LBL] = p * (float)N_EXP;
    out[OFF_Z]   = ws[128] * invT;
  }
}

extern "C" void kernel_launch(void* const* d_in, const int* in_sizes, int n_in,
                              void* d_out, int out_size, void* d_ws, size_t ws_size,
                              hipStream_t stream) {
  const float* x = (const float*)d_in[0];
  const float* w = (const float*)d_in[1];
  float* out = (float*)d_out;
  float* ws  = (float*)d_ws;
  unsigned short* whi = (unsigned short*)(ws + WS_WHI_F);
  unsigned short* wlo = (unsigned short*)(ws + WS_WLO_F);

  (void)hipMemsetAsync(d_ws, 0, 129 * sizeof(float), stream);
  split_w_kernel<<<(N_EXP * DIM) / 256, 256, 0, stream>>>(w, whi, wlo);
  router_kernel<<<N_TOKENS / TOKB, 512, 0, stream>>>(x, whi, wlo, out, ws);
  finalize_kernel<<<1, 64, 0, stream>>>(ws, out);
}

// Round 20
// 84.402 us; speedup vs baseline: 1.0492x; 1.0492x over previous
//
#include <hip/hip_runtime.h>
#include <hip/hip_bf16.h>

typedef __attribute__((ext_vector_type(8))) short bf16x8;
typedef __attribute__((ext_vector_type(4))) float f32x4;

#define N_TOKENS 16384
#define DIM 4096
#define TOKB 32            // tokens per block
#define BK 128             // K floats per staged tile
#define NIT (DIM / BK)     // 32 iterations (16 supersteps)
#define NBUF 4
#define BUF_F (TOKB * BK)  // 4096 floats (16 KB) per buffer
#define N_EXP 64

// d_out layout (all float32):
//   [0, 32768)              topk_experts as float  [token][2]
//   [32768, 65536)          combine_weight         [token][2]
//   [65536, 65536+1048576)  scores                 [token][64]
//   [1114112]               load_balance_loss
//   [1114113]               z_loss
#define OFF_W   (N_TOKENS * 2)
#define OFF_S   (N_TOKENS * 4)
#define OFF_LBL (N_TOKENS * 4 + N_TOKENS * N_EXP)
#define OFF_Z   (OFF_LBL + 1)

// ws layout (floats): [0..63] me, [64..127] ce, [128] z,
// [512..) w_hi packed ushort[64*4096] (512 KB), then w_lo packed ushort[64*4096]
#define WS_WHI_F 512
#define WS_WLO_F (512 + (N_EXP * DIM) / 2)

typedef const __attribute__((address_space(1))) void GV;
typedef __attribute__((address_space(3))) void LV;

// ---- cheap truncation split: f = hi + r exactly; lo = trunc(r). ~3 VALU/elem.
__device__ __forceinline__ unsigned int pkhi(float a, float b) {
  return __builtin_amdgcn_perm(__float_as_uint(b), __float_as_uint(a), 0x07060302u);
}
__device__ __forceinline__ float resid(float f) {
  return f - __uint_as_float(__float_as_uint(f) & 0xFFFF0000u);
}
__device__ __forceinline__ void tsplit8(const f32x4 p0, const f32x4 p1,
                                        bf16x8& hi, bf16x8& lo) {
  uint4 H = make_uint4(pkhi(p0[0], p0[1]), pkhi(p0[2], p0[3]),
                       pkhi(p1[0], p1[1]), pkhi(p1[2], p1[3]));
  float r0 = resid(p0[0]), r1 = resid(p0[1]), r2 = resid(p0[2]), r3 = resid(p0[3]);
  float r4 = resid(p1[0]), r5 = resid(p1[1]), r6 = resid(p1[2]), r7 = resid(p1[3]);
  uint4 L = make_uint4(pkhi(r0, r1), pkhi(r2, r3), pkhi(r4, r5), pkhi(r6, r7));
  hi = __builtin_bit_cast(bf16x8, H);
  lo = __builtin_bit_cast(bf16x8, L);
}

// pre-pass: w fp32 -> bf16 hi/lo planes, PRE-PACKED into MFMA fragment order.
// plane layout: [kq(4)][q(2)][it(32)][n(2)][lane(64)*8 ushorts]
__global__ __launch_bounds__(256) void split_w_kernel(
    const float* __restrict__ w,
    unsigned short* __restrict__ whi, unsigned short* __restrict__ wlo)
{
  const int i = blockIdx.x * 256 + threadIdx.x;  // 0 .. 64*4096-1
  const int e = i >> 12, k = i & 4095;
  float f = w[i];
  unsigned short h = __builtin_bit_cast(unsigned short, __float2bfloat16(f));
  float hf = __uint_as_float(((unsigned)h) << 16);
  unsigned short l = __builtin_bit_cast(unsigned short, __float2bfloat16(f - hf));
  const int q = e >> 5, n = (e >> 4) & 1, r15 = e & 15;
  const int it = k >> 7, kq = (k >> 5) & 3, half = (k >> 3) & 3, j = k & 7;
  const int lane = half * 16 + r15;
  const int idx = (((kq * 2 + q) * 32 + it) * 1024) + n * 512 + lane * 8 + j;
  whi[idx] = h;
  wlo[idx] = l;
}

__global__ __launch_bounds__(512, 4) void router_kernel(
    const float* __restrict__ x,
    const unsigned short* __restrict__ whi, const unsigned short* __restrict__ wlo,
    float* __restrict__ out, float* __restrict__ ws)
{
  // 4 linear fp32 x-tile buffers [32][128] (64 KB); reused as logits in epilogue.
  // Content is source-swizzled at 16B granularity: LDS[row][u] = x[row][u ^ (row&7)]
  __shared__ __align__(16) float smem[NBUF * BUF_F];

  const int tid  = threadIdx.x;
  const int lane = tid & 63;
  const int wv   = __builtin_amdgcn_readfirstlane(tid >> 6);  // 0..7, wave-uniform
  const int q    = wv & 1;     // expert half (32 experts)
  const int kq   = wv >> 1;    // k-slice: 0..3 (32 floats each within BK)
  const int half = lane >> 4;  // 0..3
  const int r15  = lane & 15;
  const int tok0 = blockIdx.x * TOKB;

  // staging: wave wv covers rows wv*4..+3 of the [32][128] tile
  const int row0 = wv * 4 + (lane >> 5);
  const int row1 = row0 + 2;
  const int sU   = lane & 31;
  const float* g0 = x + (size_t)(tok0 + row0) * DIM + ((sU ^ (row0 & 7)) << 2);
  const float* g1 = x + (size_t)(tok0 + row1) * DIM + ((sU ^ (row1 & 7)) << 2);
  float* const ldst = smem + wv * 512;  // wave-uniform

#define STAGE(buf, it_) do {                                                  \
    const float* s0_ = g0 + (size_t)(it_) * BK;                               \
    const float* s1_ = g1 + (size_t)(it_) * BK;                               \
    float* d_ = ldst + (buf) * BUF_F;                                         \
    __builtin_amdgcn_global_load_lds((GV*)s0_, (LV*)d_,       16, 0, 0);      \
    __builtin_amdgcn_global_load_lds((GV*)s1_, (LV*)(d_+256), 16, 0, 0);      \
  } while (0)

  // packed w: this wave's contiguous 64 KB region per plane, walked linearly
  const unsigned short* wph = whi + ((kq * 2 + q) << 15);  // *32768 ushorts
  const unsigned short* wpl = wlo + ((kq * 2 + q) << 15);
  const int lo16 = lane * 8;  // lane's 16B slot within each 1KB cell

  f32x4 acc[2][2];
#pragma unroll
  for (int tt = 0; tt < 2; ++tt)
#pragma unroll
    for (int n = 0; n < 2; ++n) acc[tt][n] = (f32x4){0.f, 0.f, 0.f, 0.f};

#define COMPUTE(itc, BH0, BH1, BL0, BL1) do {                                  \
    const float* bufp = smem + ((itc) & 3) * BUF_F;                            \
    _Pragma("unroll")                                                          \
    for (int tt = 0; tt < 2; ++tt) {                                           \
      const int rowA = tt * 16 + r15;                                          \
      const int g    = r15 & 7;                                                \
      const float* rp = bufp + rowA * BK;                                      \
      const int u0 = kq * 8 + ((half * 2) ^ g);                                \
      const int u1 = kq * 8 + ((half * 2 + 1) ^ g);                            \
      f32x4 p0 = *(const f32x4*)(rp + (u0 << 2));                              \
      f32x4 p1 = *(const f32x4*)(rp + (u1 << 2));                              \
      bf16x8 ah, al;                                                           \
      tsplit8(p0, p1, ah, al);                                                 \
      acc[tt][0] = __builtin_amdgcn_mfma_f32_16x16x32_bf16(ah, BH0, acc[tt][0], 0, 0, 0); \
      acc[tt][0] = __builtin_amdgcn_mfma_f32_16x16x32_bf16(al, BH0, acc[tt][0], 0, 0, 0); \
      acc[tt][0] = __builtin_amdgcn_mfma_f32_16x16x32_bf16(ah, BL0, acc[tt][0], 0, 0, 0); \
      acc[tt][1] = __builtin_amdgcn_mfma_f32_16x16x32_bf16(ah, BH1, acc[tt][1], 0, 0, 0); \
      acc[tt][1] = __builtin_amdgcn_mfma_f32_16x16x32_bf16(al, BH1, acc[tt][1], 0, 0, 0); \
      acc[tt][1] = __builtin_amdgcn_mfma_f32_16x16x32_bf16(ah, BL1, acc[tt][1], 0, 0, 0); \
    }                                                                          \
  } while (0)

  // ---- prologue: FIFO = stage0(2), stage1(2) ----
  STAGE(0, 0);
  STAGE(1, 1);

  for (int s = 0; s < NIT / 2; ++s) {
    const int it0 = 2 * s, it1 = 2 * s + 1;

    // 8 coalesced w-loads for it0 and it1 (1 KB contiguous per wave each)
    const unsigned short* ph0 = wph + it0 * 1024;
    const unsigned short* pl0 = wpl + it0 * 1024;
    const unsigned short* ph1 = wph + it1 * 1024;
    const unsigned short* pl1 = wpl + it1 * 1024;
    bf16x8 Abh0 = *(const bf16x8*)(ph0 + lo16);
    bf16x8 Abh1 = *(const bf16x8*)(ph0 + 512 + lo16);
    bf16x8 Abl0 = *(const bf16x8*)(pl0 + lo16);
    bf16x8 Abl1 = *(const bf16x8*)(pl0 + 512 + lo16);
    bf16x8 Bbh0 = *(const bf16x8*)(ph1 + lo16);
    bf16x8 Bbh1 = *(const bf16x8*)(ph1 + 512 + lo16);
    bf16x8 Bbl0 = *(const bf16x8*)(pl1 + lo16);
    bf16x8 Bbl1 = *(const bf16x8*)(pl1 + 512 + lo16);

    // retire the previous superstep's 4 stage-ops (the buffers we now read);
    // this superstep's 8 w-loads stay in flight.
    asm volatile("s_waitcnt vmcnt(8)" ::: "memory");
    __builtin_amdgcn_s_barrier();

    // stages for it0+2 / it1+2 (post-barrier => WAR-safe at NBUF=4;
    // waited at next superstep's vmcnt => ~2 iterations of cover)
    STAGE((it0 + 2) & 3, (it0 + 2 < NIT) ? it0 + 2 : NIT - 1);
    STAGE((it1 + 2) & 3, (it1 + 2 < NIT) ? it1 + 2 : NIT - 1);

    COMPUTE(it0, Abh0, Abh1, Abl0, Abl1);
    COMPUTE(it1, Bbh0, Bbh1, Bbl0, Bbl1);
  }

  // drain all outstanding gll writes (incl. clamped tail stages) before smem reuse
  asm volatile("s_waitcnt vmcnt(0)" ::: "memory");
  __syncthreads();

  // ---- epilogue: reuse smem as 4 kq-partial logit buffers [32][65] ----
  float* lb = smem;
  {
    float* dst = lb + kq * (TOKB * 65);
#pragma unroll
    for (int tt = 0; tt < 2; ++tt) {
#pragma unroll
      for (int n = 0; n < 2; ++n) {
#pragma unroll
        for (int r = 0; r < 4; ++r) {
          dst[(tt * 16 + half * 4 + r) * 65 + q * 32 + n * 16 + r15] = acc[tt][n][r];
        }
      }
    }
  }
  __syncthreads();

  // combine the four kq partials
  for (int i = tid; i < TOKB * 64; i += 512) {
    const int t = i >> 6, e = i & 63;
    lb[t * 65 + e] += lb[2080 + t * 65 + e] + lb[4160 + t * 65 + e] + lb[6240 + t * 65 + e];
  }
  __syncthreads();

  if (wv == 0 && lane < TOKB) {
    // lane owns one token: full softmax + top-2 + z-loss
    const int token = tok0 + lane;
    float v[64];
#pragma unroll
    for (int e = 0; e < 64; ++e) v[e] = lb[lane * 65 + e];
    float m = v[0];
#pragma unroll
    for (int e = 1; e < 64; ++e) m = fmaxf(m, v[e]);
    float sum = 0.f;
#pragma unroll
    for (int e = 0; e < 64; ++e) { v[e] = expf(v[e] - m); sum += v[e]; }
    const float inv = 1.0f / sum;
    float m1 = -1.f, m2 = -1.f;
    int   i1 = 0,    i2 = 0;
#pragma unroll
    for (int e = 0; e < 64; ++e) {
      float sc = v[e] * inv;
      lb[lane * 65 + e] = sc;
      if (sc > m1)      { m2 = m1; i2 = i1; m1 = sc; i1 = e; }
      else if (sc > m2) { m2 = sc; i2 = e; }
    }
    out[2 * token]         = (float)i1;
    out[2 * token + 1]     = (float)i2;
    out[OFF_W + 2 * token]     = m1;
    out[OFF_W + 2 * token + 1] = m2;

    float lse = m + logf(sum);
    float z = lse * lse;
#pragma unroll
    for (int off = 16; off > 0; off >>= 1) z += __shfl_down(z, off);
    if (lane == 0) atomicAdd(ws + 128, z);
  }
  __syncthreads();

  // coalesced scores store for this block's 32 tokens
  float* outS = out + OFF_S + (size_t)blockIdx.x * TOKB * 64;
  for (int i = tid; i < TOKB * 64; i += 512) {
    outS[i] = lb[(i >> 6) * 65 + (i & 63)];
  }

  // per-expert partial me / ce for this block's tokens (expert = lane)
  if (wv == 0) {
    float sm = 0.f, cn = 0.f;
#pragma unroll
    for (int t = 0; t < TOKB; ++t) {
      float sc = lb[t * 65 + lane];
      sm += sc;
      cn += (sc > 0.f) ? 1.f : 0.f;
    }
    atomicAdd(ws + lane, sm);
    atomicAdd(ws + 64 + lane, cn);
  }
#undef STAGE
#undef COMPUTE
}

__global__ void finalize_kernel(const float* __restrict__ ws, float* __restrict__ out) {
  const int l = threadIdx.x;  // 64 threads
  const float invT = 1.0f / (float)N_TOKENS;
  float me = ws[l] * invT;
  float ce = ws[64 + l] * invT;
  float p = me * ce;
#pragma unroll
  for (int off = 32; off > 0; off >>= 1) p += __shfl_down(p, off);
  if (l == 0) {
    out[OFF_LBL] = p * (float)N_EXP;
    out[OFF_Z]   = ws[128] * invT;
  }
}

extern "C" void kernel_launch(void* const* d_in, const int* in_sizes, int n_in,
                              void* d_out, int out_size, void* d_ws, size_t ws_size,
                              hipStream_t stream) {
  const float* x = (const float*)d_in[0];
  const float* w = (const float*)d_in[1];
  float* out = (float*)d_out;
  float* ws  = (float*)d_ws;
  unsigned short* whi = (unsigned short*)(ws + WS_WHI_F);
  unsigned short* wlo = (unsigned short*)(ws + WS_WLO_F);

  (void)hipMemsetAsync(d_ws, 0, 129 * sizeof(float), stream);
  split_w_kernel<<<(N_EXP * DIM) / 256, 256, 0, stream>>>(w, whi, wlo);
  router_kernel<<<N_TOKENS / TOKB, 512, 0, stream>>>(x, whi, wlo, out, ws);
  finalize_kernel<<<1, 64, 0, stream>>>(ws, out);
}

// Round 21
// 81.501 us; speedup vs baseline: 1.0866x; 1.0356x over previous
//
#include <hip/hip_runtime.h>
#include <hip/hip_bf16.h>

typedef __attribute__((ext_vector_type(8))) short bf16x8;
typedef __attribute__((ext_vector_type(4))) float f32x4;

#define N_TOKENS 16384
#define DIM 4096
#define TOKB 32            // tokens per block
#define NIT 32             // iterations = 16 k-chunks x 2 row-halves
#define NBUF 4
#define BUF_F (16 * 256)   // 16 rows x 256 floats = 16 KB per buffer
#define N_EXP 64

// d_out layout (all float32):
//   [0, 32768)              topk_experts as float  [token][2]
//   [32768, 65536)          combine_weight         [token][2]
//   [65536, 65536+1048576)  scores                 [token][64]
//   [1114112]               load_balance_loss
//   [1114113]               z_loss
#define OFF_W   (N_TOKENS * 2)
#define OFF_S   (N_TOKENS * 4)
#define OFF_LBL (N_TOKENS * 4 + N_TOKENS * N_EXP)
#define OFF_Z   (OFF_LBL + 1)

// ws layout (floats): [0..63] me, [64..127] ce, [128] z,
// [512..) w_hi packed ushort[64*4096] (512 KB), then w_lo packed ushort[64*4096]
#define WS_WHI_F 512
#define WS_WLO_F (512 + (N_EXP * DIM) / 2)

typedef const __attribute__((address_space(1))) void GV;
typedef __attribute__((address_space(3))) void LV;

// ---- cheap truncation split: f = hi + r exactly; lo = trunc(r). ~3 VALU/elem.
__device__ __forceinline__ unsigned int pkhi(float a, float b) {
  return __builtin_amdgcn_perm(__float_as_uint(b), __float_as_uint(a), 0x07060302u);
}
__device__ __forceinline__ float resid(float f) {
  return f - __uint_as_float(__float_as_uint(f) & 0xFFFF0000u);
}
__device__ __forceinline__ void tsplit8(const f32x4 p0, const f32x4 p1,
                                        bf16x8& hi, bf16x8& lo) {
  uint4 H = make_uint4(pkhi(p0[0], p0[1]), pkhi(p0[2], p0[3]),
                       pkhi(p1[0], p1[1]), pkhi(p1[2], p1[3]));
  float r0 = resid(p0[0]), r1 = resid(p0[1]), r2 = resid(p0[2]), r3 = resid(p0[3]);
  float r4 = resid(p1[0]), r5 = resid(p1[1]), r6 = resid(p1[2]), r7 = resid(p1[3]);
  uint4 L = make_uint4(pkhi(r0, r1), pkhi(r2, r3), pkhi(r4, r5), pkhi(r6, r7));
  hi = __builtin_bit_cast(bf16x8, H);
  lo = __builtin_bit_cast(bf16x8, L);
}

// pre-pass: w fp32 -> bf16 hi/lo planes, PRE-PACKED into MFMA fragment order.
// plane layout: [kq(4)][q(2)][kc(16)][j(2)][n(2)][lane(64)*8 ushorts]
//   source (e,k): q=e>>5, n=(e>>4)&1, r15=e&15; kc=k>>8, kq=(k>>6)&3,
//   j=(k>>5)&1, half=(k>>3)&3, jj=k&7; lane = half*16 + r15.
__global__ __launch_bounds__(256) void split_w_kernel(
    const float* __restrict__ w,
    unsigned short* __restrict__ whi, unsigned short* __restrict__ wlo)
{
  const int i = blockIdx.x * 256 + threadIdx.x;  // 0 .. 64*4096-1
  const int e = i >> 12, k = i & 4095;
  float f = w[i];
  unsigned short h = __builtin_bit_cast(unsigned short, __float2bfloat16(f));
  float hf = __uint_as_float(((unsigned)h) << 16);
  unsigned short l = __builtin_bit_cast(unsigned short, __float2bfloat16(f - hf));
  const int q = e >> 5, n = (e >> 4) & 1, r15 = e & 15;
  const int kc = k >> 8, kq = (k >> 6) & 3, j = (k >> 5) & 1, half = (k >> 3) & 3,
            jj = k & 7;
  const int lane = half * 16 + r15;
  const int idx = ((kq * 2 + q) << 15) + kc * 2048 + (j * 2 + n) * 512 + lane * 8 + jj;
  whi[idx] = h;
  wlo[idx] = l;
}

__global__ __launch_bounds__(512, 4) void router_kernel(
    const float* __restrict__ x,
    const unsigned short* __restrict__ whi, const unsigned short* __restrict__ wlo,
    float* __restrict__ out, float* __restrict__ ws)
{
  // 4 fp32 x-tile buffers [16 rows][256 floats] (64 KB); reused as logits later.
  // LDS[row][u] = x[row][u ^ (row&7)] at 16B-unit granularity (involution).
  __shared__ __align__(16) float smem[NBUF * BUF_F];

  const int tid  = threadIdx.x;
  const int lane = tid & 63;
  const int wv   = __builtin_amdgcn_readfirstlane(tid >> 6);  // 0..7, wave-uniform
  const int q    = wv & 1;     // expert half (32 experts)
  const int kq   = wv >> 1;    // 64-float k-slice within 256-chunk: 0..3
  const int half = lane >> 4;  // 0..3
  const int r15  = lane & 15;
  const int g8   = r15 & 7;
  const int tok0 = blockIdx.x * TOKB;

  // staging: wave wv owns local rows 2wv, 2wv+1 of the 16-row tile;
  // one gll = one row x 1 KB fully contiguous (64 lanes x 16 B)
  const int rl0 = 2 * wv, rl1 = 2 * wv + 1;
  const float* gs00 = x + (size_t)(tok0 + rl0) * DIM      + ((lane ^ (rl0 & 7)) << 2);
  const float* gs01 = x + (size_t)(tok0 + rl1) * DIM      + ((lane ^ (rl1 & 7)) << 2);
  const float* gs10 = x + (size_t)(tok0 + 16 + rl0) * DIM + ((lane ^ (rl0 & 7)) << 2);
  const float* gs11 = x + (size_t)(tok0 + 16 + rl1) * DIM + ((lane ^ (rl1 & 7)) << 2);
  float* const ldst = smem + wv * 512;  // row rl0 offset within a buffer

#define STAGE(buf, it_) do {                                                  \
    const int rh_ = (it_) & 1;                                                \
    const size_t ko_ = (size_t)((it_) >> 1) * 256;                            \
    const float* s0_ = (rh_ ? gs10 : gs00) + ko_;                             \
    const float* s1_ = (rh_ ? gs11 : gs01) + ko_;                             \
    float* d_ = ldst + (buf) * BUF_F;                                         \
    __builtin_amdgcn_global_load_lds((GV*)s0_, (LV*)d_,       16, 0, 0);      \
    __builtin_amdgcn_global_load_lds((GV*)s1_, (LV*)(d_+256), 16, 0, 0);      \
  } while (0)

  // packed w: this wave's contiguous 64 KB region per plane; 4 KB per k-chunk
  const unsigned short* wph = whi + ((kq * 2 + q) << 15);
  const unsigned short* wpl = wlo + ((kq * 2 + q) << 15);
  const int lo16 = lane * 8;

  f32x4 acc0[2], acc1[2];  // [rh][n], static names (rule #20)
#pragma unroll
  for (int n = 0; n < 2; ++n) {
    acc0[n] = (f32x4){0.f, 0.f, 0.f, 0.f};
    acc1[n] = (f32x4){0.f, 0.f, 0.f, 0.f};
  }

#define COMPUTE(itc, ACC, H00, H01, H10, H11, L00, L01, L10, L11) do {         \
    const float* rp = smem + ((itc) & 3) * BUF_F + r15 * 256;                  \
    /* j = 0 */ {                                                              \
      const int u0 = kq * 16 + ((half * 2) ^ g8);                              \
      const int u1 = kq * 16 + ((half * 2 + 1) ^ g8);                          \
      f32x4 p0 = *(const f32x4*)(rp + (u0 << 2));                              \
      f32x4 p1 = *(const f32x4*)(rp + (u1 << 2));                              \
      bf16x8 ah, al;                                                           \
      tsplit8(p0, p1, ah, al);                                                 \
      ACC[0] = __builtin_amdgcn_mfma_f32_16x16x32_bf16(ah, H00, ACC[0], 0, 0, 0); \
      ACC[0] = __builtin_amdgcn_mfma_f32_16x16x32_bf16(al, H00, ACC[0], 0, 0, 0); \
      ACC[0] = __builtin_amdgcn_mfma_f32_16x16x32_bf16(ah, L00, ACC[0], 0, 0, 0); \
      ACC[1] = __builtin_amdgcn_mfma_f32_16x16x32_bf16(ah, H01, ACC[1], 0, 0, 0); \
      ACC[1] = __builtin_amdgcn_mfma_f32_16x16x32_bf16(al, H01, ACC[1], 0, 0, 0); \
      ACC[1] = __builtin_amdgcn_mfma_f32_16x16x32_bf16(ah, L01, ACC[1], 0, 0, 0); \
    }                                                                          \
    /* j = 1 */ {                                                              \
      const int u0 = kq * 16 + 8 + ((half * 2) ^ g8);                          \
      const int u1 = kq * 16 + 8 + ((half * 2 + 1) ^ g8);                      \
      f32x4 p0 = *(const f32x4*)(rp + (u0 << 2));                              \
      f32x4 p1 = *(const f32x4*)(rp + (u1 << 2));                              \
      bf16x8 ah, al;                                                           \
      tsplit8(p0, p1, ah, al);                                                 \
      ACC[0] = __builtin_amdgcn_mfma_f32_16x16x32_bf16(ah, H10, ACC[0], 0, 0, 0); \
      ACC[0] = __builtin_amdgcn_mfma_f32_16x16x32_bf16(al, H10, ACC[0], 0, 0, 0); \
      ACC[0] = __builtin_amdgcn_mfma_f32_16x16x32_bf16(ah, L10, ACC[0], 0, 0, 0); \
      ACC[1] = __builtin_amdgcn_mfma_f32_16x16x32_bf16(ah, H11, ACC[1], 0, 0, 0); \
      ACC[1] = __builtin_amdgcn_mfma_f32_16x16x32_bf16(al, H11, ACC[1], 0, 0, 0); \
      ACC[1] = __builtin_amdgcn_mfma_f32_16x16x32_bf16(ah, L11, ACC[1], 0, 0, 0); \
    }                                                                          \
  } while (0)

  // ---- prologue: FIFO = stage0(2), stage1(2) ----
  STAGE(0, 0);
  STAGE(1, 1);

  for (int s = 0; s < NIT / 2; ++s) {
    const int it0 = 2 * s, it1 = 2 * s + 1;

    // 8 w-loads for k-chunk s (4 KB contiguous per plane; shared by both rh)
    const unsigned short* ph = wph + s * 2048;
    const unsigned short* pl = wpl + s * 2048;
    bf16x8 H00 = *(const bf16x8*)(ph + lo16);
    bf16x8 H01 = *(const bf16x8*)(ph + 512 + lo16);
    bf16x8 H10 = *(const bf16x8*)(ph + 1024 + lo16);
    bf16x8 H11 = *(const bf16x8*)(ph + 1536 + lo16);
    bf16x8 L00 = *(const bf16x8*)(pl + lo16);
    bf16x8 L01 = *(const bf16x8*)(pl + 512 + lo16);
    bf16x8 L10 = *(const bf16x8*)(pl + 1024 + lo16);
    bf16x8 L11 = *(const bf16x8*)(pl + 1536 + lo16);

    // stage it0+2 (pre-barrier, r18's winning placement)
    STAGE((it0 + 2) & 3, (it0 + 2 < NIT) ? it0 + 2 : NIT - 1);

    // outstanding = stage(it0)(2)+stage(it1)(2)+w(8)+stage(it0+2)(2) = 14;
    // vmcnt(12) retires exactly stage(it0) (count-based, order-robust).
    asm volatile("s_waitcnt vmcnt(12)" ::: "memory");
    __builtin_amdgcn_s_barrier();
    COMPUTE(it0, acc0, H00, H01, H10, H11, L00, L01, L10, L11);

    // stage it1+2; w all consumed above -> outstanding = 3 stage pairs = 6;
    // vmcnt(4) retires exactly stage(it1).
    STAGE((it1 + 2) & 3, (it1 + 2 < NIT) ? it1 + 2 : NIT - 1);
    asm volatile("s_waitcnt vmcnt(4)" ::: "memory");
    __builtin_amdgcn_s_barrier();
    COMPUTE(it1, acc1, H00, H01, H10, H11, L00, L01, L10, L11);
  }

  // drain all outstanding gll writes (incl. clamped tail stages) before smem reuse
  asm volatile("s_waitcnt vmcnt(0)" ::: "memory");
  __syncthreads();

  // ---- epilogue: reuse smem as 4 kq-partial logit buffers [32][65] ----
  float* lb = smem;
  {
    float* dst = lb + kq * (TOKB * 65);
#pragma unroll
    for (int n = 0; n < 2; ++n) {
#pragma unroll
      for (int r = 0; r < 4; ++r) {
        dst[(half * 4 + r) * 65 + q * 32 + n * 16 + r15]      = acc0[n][r];
        dst[(16 + half * 4 + r) * 65 + q * 32 + n * 16 + r15] = acc1[n][r];
      }
    }
  }
  __syncthreads();

  // combine the four kq partials
  for (int i = tid; i < TOKB * 64; i += 512) {
    const int t = i >> 6, e = i & 63;
    lb[t * 65 + e] += lb[2080 + t * 65 + e] + lb[4160 + t * 65 + e] + lb[6240 + t * 65 + e];
  }
  __syncthreads();

  if (wv == 0 && lane < TOKB) {
    // lane owns one token: full softmax + top-2 + z-loss
    const int token = tok0 + lane;
    float v[64];
#pragma unroll
    for (int e = 0; e < 64; ++e) v[e] = lb[lane * 65 + e];
    float m = v[0];
#pragma unroll
    for (int e = 1; e < 64; ++e) m = fmaxf(m, v[e]);
    float sum = 0.f;
#pragma unroll
    for (int e = 0; e < 64; ++e) { v[e] = expf(v[e] - m); sum += v[e]; }
    const float inv = 1.0f / sum;
    float m1 = -1.f, m2 = -1.f;
    int   i1 = 0,    i2 = 0;
#pragma unroll
    for (int e = 0; e < 64; ++e) {
      float sc = v[e] * inv;
      lb[lane * 65 + e] = sc;
      if (sc > m1)      { m2 = m1; i2 = i1; m1 = sc; i1 = e; }
      else if (sc > m2) { m2 = sc; i2 = e; }
    }
    out[2 * token]         = (float)i1;
    out[2 * token + 1]     = (float)i2;
    out[OFF_W + 2 * token]     = m1;
    out[OFF_W + 2 * token + 1] = m2;

    float lse = m + logf(sum);
    float z = lse * lse;
#pragma unroll
    for (int off = 16; off > 0; off >>= 1) z += __shfl_down(z, off);
    if (lane == 0) atomicAdd(ws + 128, z);
  }
  __syncthreads();

  // coalesced scores store for this block's 32 tokens
  float* outS = out + OFF_S + (size_t)blockIdx.x * TOKB * 64;
  for (int i = tid; i < TOKB * 64; i += 512) {
    outS[i] = lb[(i >> 6) * 65 + (i & 63)];
  }

  // per-expert partial me / ce for this block's tokens (expert = lane)
  if (wv == 0) {
    float sm = 0.f, cn = 0.f;
#pragma unroll
    for (int t = 0; t < TOKB; ++t) {
      float sc = lb[t * 65 + lane];
      sm += sc;
      cn += (sc > 0.f) ? 1.f : 0.f;
    }
    atomicAdd(ws + lane, sm);
    atomicAdd(ws + 64 + lane, cn);
  }
#undef STAGE
#undef COMPUTE
}

__global__ void finalize_kernel(const float* __restrict__ ws, float* __restrict__ out) {
  const int l = threadIdx.x;  // 64 threads
  const float invT = 1.0f / (float)N_TOKENS;
  float me = ws[l] * invT;
  float ce = ws[64 + l] * invT;
  float p = me * ce;
#pragma unroll
  for (int off = 32; off > 0; off >>= 1) p += __shfl_down(p, off);
  if (l == 0) {
    out[OFF_LBL] = p * (float)N_EXP;
    out[OFF_Z]   = ws[128] * invT;
  }
}

extern "C" void kernel_launch(void* const* d_in, const int* in_sizes, int n_in,
                              void* d_out, int out_size, void* d_ws, size_t ws_size,
                              hipStream_t stream) {
  const float* x = (const float*)d_in[0];
  const float* w = (const float*)d_in[1];
  float* out = (float*)d_out;
  float* ws  = (float*)d_ws;
  unsigned short* whi = (unsigned short*)(ws + WS_WHI_F);
  unsigned short* wlo = (unsigned short*)(ws + WS_WLO_F);

  (void)hipMemsetAsync(d_ws, 0, 129 * sizeof(float), stream);
  split_w_kernel<<<(N_EXP * DIM) / 256, 256, 0, stream>>>(w, whi, wlo);
  router_kernel<<<N_TOKENS / TOKB, 512, 0, stream>>>(x, whi, wlo, out, ws);
  finalize_kernel<<<1, 64, 0, stream>>>(ws, out);
}